// Round 1
// baseline (48.289 us; speedup 1.0000x reference)
//
#include <hip/hip_runtime.h>

namespace {
constexpr int kB = 2048;
constexpr int kF = 64;
constexpr int kC = 10;
constexpr int kS = 5;
constexpr int kH1 = 32;
constexpr int kH2 = 16;
constexpr float kWCat = 0.7f / kC;   // per-cat-group weight (mean over C, HIER_W)
constexpr float kWSub = 0.3f / kS;   // per-sub-group weight
constexpr int kNB = 8;               // batch elements per thread (2048 / 256)
constexpr int kThreads = 256;
}

// Kernel A: transpose features (B,F)->(F,B) into ws (coalesced b-reads later),
// and initialize out[b] with the weighted bias terms.
__global__ void prep_kernel(const float* __restrict__ x,
                            const float* __restrict__ cat_bias,
                            const float* __restrict__ sub_bias,
                            float* __restrict__ xT, int do_transpose,
                            float* __restrict__ out) {
    int tid = blockIdx.x * blockDim.x + threadIdx.x;
    if (do_transpose && tid < kB * kF) {
        int b = tid / kF, f = tid % kF;
        xT[f * kB + b] = x[tid];
    }
    if (tid < kB) {
        float acc = 0.f;
        for (int g = 0; g < kC; ++g) acc += cat_bias[g] * kWCat;
        for (int g = 0; g < kS; ++g) acc += sub_bias[g] * kWSub;
        out[tid] = acc;
    }
}

// Kernel B: one block per (group, feature) pair. 15*64 = 960 blocks.
// Weights for the pair staged in LDS; each thread owns 8 batch elems.
__global__ __launch_bounds__(kThreads, 2) void nam_kernel(
    const float* __restrict__ x, int trans,
    const float* __restrict__ cW1, const float* __restrict__ cB1,
    const float* __restrict__ cW2, const float* __restrict__ cB2,
    const float* __restrict__ cW3, const float* __restrict__ cB3,
    const float* __restrict__ gW1, const float* __restrict__ gB1,
    const float* __restrict__ gW2, const float* __restrict__ gB2,
    const float* __restrict__ gW3, const float* __restrict__ gB3,
    float* __restrict__ out) {
    const int p = blockIdx.x;
    const int gg = p / kF;   // 0..14: 0..9 cat, 10..14 sub
    const int f  = p % kF;

    const float* W1; const float* B1; const float* W2; const float* B2;
    const float* W3; const float* B3; float wgt;
    if (gg < kC) {
        const int base = gg * kF + f;
        W1 = cW1 + base * kH1;       B1 = cB1 + base * kH1;
        W2 = cW2 + base * kH1 * kH2; B2 = cB2 + base * kH2;
        W3 = cW3 + base * kH2;       B3 = cB3 + base;
        wgt = kWCat;
    } else {
        const int base = (gg - kC) * kF + f;
        W1 = gW1 + base * kH1;       B1 = gB1 + base * kH1;
        W2 = gW2 + base * kH1 * kH2; B2 = gB2 + base * kH2;
        W3 = gW3 + base * kH2;       B3 = gB3 + base;
        wgt = kWSub;
    }

    __shared__ float lW2[kH1 * kH2];   // 512 floats, 2 KB
    __shared__ float lW1[kH1], lB1[kH1], lB2[kH2], lW3[kH2];
    __shared__ float lB3;
    const int t = threadIdx.x;
    lW2[t] = W2[t];
    lW2[t + 256] = W2[t + 256];
    if (t < kH1) { lW1[t] = W1[t]; lB1[t] = B1[t]; }
    if (t < kH2) { lB2[t] = B2[t]; lW3[t] = W3[t]; }
    if (t == 0) { lB3 = B3[0]; }
    __syncthreads();

    // Load this feature's column of x for my 8 batch elems.
    float xb[kNB];
    if (trans) {
        const float* xcol = x + f * kB;
        #pragma unroll
        for (int i = 0; i < kNB; ++i) xb[i] = xcol[t + i * kThreads];
    } else {
        #pragma unroll
        for (int i = 0; i < kNB; ++i) xb[i] = x[(t + i * kThreads) * kF + f];
    }

    // h2 pre-activation accumulators, init with b2.
    float acc[kNB][kH2];
    #pragma unroll
    for (int i = 0; i < kNB; ++i)
        #pragma unroll
        for (int k = 0; k < kH2; ++k) acc[i][k] = lB2[k];

    // Layer 1 fused into layer 2: for each hidden unit h, compute
    // h1 = relu(x*w1+b1) for 8 b's, then rank-1 update of acc with W2 row h.
    for (int h = 0; h < kH1; ++h) {
        const float w1 = lW1[h], b1 = lB1[h];
        float h1v[kNB];
        #pragma unroll
        for (int i = 0; i < kNB; ++i) h1v[i] = fmaxf(fmaf(xb[i], w1, b1), 0.f);
        const float4 r0 = *(const float4*)&lW2[h * kH2 + 0];
        const float4 r1 = *(const float4*)&lW2[h * kH2 + 4];
        const float4 r2 = *(const float4*)&lW2[h * kH2 + 8];
        const float4 r3 = *(const float4*)&lW2[h * kH2 + 12];
        #pragma unroll
        for (int i = 0; i < kNB; ++i) {
            const float a = h1v[i];
            acc[i][0]  = fmaf(a, r0.x, acc[i][0]);
            acc[i][1]  = fmaf(a, r0.y, acc[i][1]);
            acc[i][2]  = fmaf(a, r0.z, acc[i][2]);
            acc[i][3]  = fmaf(a, r0.w, acc[i][3]);
            acc[i][4]  = fmaf(a, r1.x, acc[i][4]);
            acc[i][5]  = fmaf(a, r1.y, acc[i][5]);
            acc[i][6]  = fmaf(a, r1.z, acc[i][6]);
            acc[i][7]  = fmaf(a, r1.w, acc[i][7]);
            acc[i][8]  = fmaf(a, r2.x, acc[i][8]);
            acc[i][9]  = fmaf(a, r2.y, acc[i][9]);
            acc[i][10] = fmaf(a, r2.z, acc[i][10]);
            acc[i][11] = fmaf(a, r2.w, acc[i][11]);
            acc[i][12] = fmaf(a, r3.x, acc[i][12]);
            acc[i][13] = fmaf(a, r3.y, acc[i][13]);
            acc[i][14] = fmaf(a, r3.z, acc[i][14]);
            acc[i][15] = fmaf(a, r3.w, acc[i][15]);
        }
    }

    // Layer 3: relu(h2) . W3 + b3, then weighted atomic accumulate into out[b].
    #pragma unroll
    for (int i = 0; i < kNB; ++i) {
        float o = lB3;
        #pragma unroll
        for (int k = 0; k < kH2; ++k) o = fmaf(fmaxf(acc[i][k], 0.f), lW3[k], o);
        atomicAdd(&out[t + i * kThreads], wgt * o);
    }
}

extern "C" void kernel_launch(void* const* d_in, const int* in_sizes, int n_in,
                              void* d_out, int out_size, void* d_ws, size_t ws_size,
                              hipStream_t stream) {
    const float* x     = (const float*)d_in[0];
    const float* cW1   = (const float*)d_in[1];
    const float* cB1   = (const float*)d_in[2];
    const float* cW2   = (const float*)d_in[3];
    const float* cB2   = (const float*)d_in[4];
    const float* cW3   = (const float*)d_in[5];
    const float* cB3   = (const float*)d_in[6];
    const float* cbias = (const float*)d_in[7];
    const float* sW1   = (const float*)d_in[8];
    const float* sB1   = (const float*)d_in[9];
    const float* sW2   = (const float*)d_in[10];
    const float* sB2   = (const float*)d_in[11];
    const float* sW3   = (const float*)d_in[12];
    const float* sB3   = (const float*)d_in[13];
    const float* sbias = (const float*)d_in[14];
    float* out = (float*)d_out;

    float* xT = (float*)d_ws;
    const int trans = (ws_size >= (size_t)(kB * kF) * sizeof(float)) ? 1 : 0;

    prep_kernel<<<(kB * kF + 255) / 256, 256, 0, stream>>>(x, cbias, sbias, xT, trans, out);
    const float* xin = trans ? (const float*)xT : x;
    nam_kernel<<<(kC + kS) * kF, kThreads, 0, stream>>>(
        xin, trans, cW1, cB1, cW2, cB2, cW3, cB3,
        sW1, sB1, sW2, sB2, sW3, sB3, out);
}

// Round 2
// 41.493 us; speedup vs baseline: 1.1638x; 1.1638x over previous
//
#include <hip/hip_runtime.h>

namespace {
constexpr int kB = 2048;
constexpr int kF = 64;
constexpr int kC = 10;
constexpr int kS = 5;
constexpr int kH1 = 32;
constexpr int kH2 = 16;
constexpr float kWCat = 0.7f / kC;   // per-cat-group weight (mean over C, HIER_W)
constexpr float kWSub = 0.3f / kS;   // per-sub-group weight
constexpr int kNB = 4;               // batch elements per thread
constexpr int kThreads = 256;
constexpr int kChunk = kThreads * kNB;      // 1024 batch per block
constexpr int kChunksPerPair = kB / kChunk; // 2
}

// Kernel A: transpose features (B,F)->(F,B) into ws (coalesced b-reads later),
// and initialize out[b] with the weighted bias terms.
__global__ void prep_kernel(const float* __restrict__ x,
                            const float* __restrict__ cat_bias,
                            const float* __restrict__ sub_bias,
                            float* __restrict__ xT, int do_transpose,
                            float* __restrict__ out) {
    int tid = blockIdx.x * blockDim.x + threadIdx.x;
    if (do_transpose && tid < kB * kF) {
        int b = tid / kF, f = tid % kF;
        xT[f * kB + b] = x[tid];
    }
    if (tid < kB) {
        float acc = 0.f;
        for (int g = 0; g < kC; ++g) acc += cat_bias[g] * kWCat;
        for (int g = 0; g < kS; ++g) acc += sub_bias[g] * kWSub;
        out[tid] = acc;
    }
}

// Kernel B: one block per ((group,feature) pair, batch-chunk). 15*64*2 = 1920
// blocks. Weights for the pair staged in LDS; each thread owns 4 batch elems
// (acc = 64 VGPRs -> fits the <=128-VGPR / 4-waves-per-EU occupancy tier).
__global__ __launch_bounds__(kThreads, 4) void nam_kernel(
    const float* __restrict__ x, int trans,
    const float* __restrict__ cW1, const float* __restrict__ cB1,
    const float* __restrict__ cW2, const float* __restrict__ cB2,
    const float* __restrict__ cW3, const float* __restrict__ cB3,
    const float* __restrict__ gW1, const float* __restrict__ gB1,
    const float* __restrict__ gW2, const float* __restrict__ gB2,
    const float* __restrict__ gW3, const float* __restrict__ gB3,
    float* __restrict__ out) {
    const int p     = blockIdx.x >> 1;      // (group,feature) pair id
    const int chunk = blockIdx.x & 1;       // batch half
    const int gg = p / kF;                  // 0..14: 0..9 cat, 10..14 sub
    const int f  = p % kF;
    const int b0 = chunk * kChunk;

    const float* W1; const float* B1; const float* W2; const float* B2;
    const float* W3; const float* B3; float wgt;
    if (gg < kC) {
        const int base = gg * kF + f;
        W1 = cW1 + base * kH1;       B1 = cB1 + base * kH1;
        W2 = cW2 + base * kH1 * kH2; B2 = cB2 + base * kH2;
        W3 = cW3 + base * kH2;       B3 = cB3 + base;
        wgt = kWCat;
    } else {
        const int base = (gg - kC) * kF + f;
        W1 = gW1 + base * kH1;       B1 = gB1 + base * kH1;
        W2 = gW2 + base * kH1 * kH2; B2 = gB2 + base * kH2;
        W3 = gW3 + base * kH2;       B3 = gB3 + base;
        wgt = kWSub;
    }

    __shared__ float lW2[kH1 * kH2];   // 512 floats, 2 KB
    __shared__ float lW1[kH1], lB1[kH1], lB2[kH2], lW3[kH2];
    __shared__ float lB3;
    const int t = threadIdx.x;
    lW2[t] = W2[t];
    lW2[t + 256] = W2[t + 256];
    if (t < kH1) { lW1[t] = W1[t]; lB1[t] = B1[t]; }
    if (t < kH2) { lB2[t] = B2[t]; lW3[t] = W3[t]; }
    if (t == 0) { lB3 = B3[0]; }
    __syncthreads();

    // Load this feature's column of x for my 4 batch elems.
    float xb[kNB];
    if (trans) {
        const float* xcol = x + f * kB + b0;
        #pragma unroll
        for (int i = 0; i < kNB; ++i) xb[i] = xcol[t + i * kThreads];
    } else {
        #pragma unroll
        for (int i = 0; i < kNB; ++i) xb[i] = x[(b0 + t + i * kThreads) * kF + f];
    }

    // h2 pre-activation accumulators, init with b2.
    float acc[kNB][kH2];
    #pragma unroll
    for (int i = 0; i < kNB; ++i)
        #pragma unroll
        for (int k = 0; k < kH2; ++k) acc[i][k] = lB2[k];

    // Layer 1 fused into layer 2: for each hidden unit h, compute
    // h1 = relu(x*w1+b1) for 4 b's, then rank-1 update of acc with W2 row h.
    #pragma unroll 4
    for (int h = 0; h < kH1; ++h) {
        const float w1 = lW1[h], b1 = lB1[h];
        float h1v[kNB];
        #pragma unroll
        for (int i = 0; i < kNB; ++i) h1v[i] = fmaxf(fmaf(xb[i], w1, b1), 0.f);
        const float4 r0 = *(const float4*)&lW2[h * kH2 + 0];
        const float4 r1 = *(const float4*)&lW2[h * kH2 + 4];
        const float4 r2 = *(const float4*)&lW2[h * kH2 + 8];
        const float4 r3 = *(const float4*)&lW2[h * kH2 + 12];
        #pragma unroll
        for (int i = 0; i < kNB; ++i) {
            const float a = h1v[i];
            acc[i][0]  = fmaf(a, r0.x, acc[i][0]);
            acc[i][1]  = fmaf(a, r0.y, acc[i][1]);
            acc[i][2]  = fmaf(a, r0.z, acc[i][2]);
            acc[i][3]  = fmaf(a, r0.w, acc[i][3]);
            acc[i][4]  = fmaf(a, r1.x, acc[i][4]);
            acc[i][5]  = fmaf(a, r1.y, acc[i][5]);
            acc[i][6]  = fmaf(a, r1.z, acc[i][6]);
            acc[i][7]  = fmaf(a, r1.w, acc[i][7]);
            acc[i][8]  = fmaf(a, r2.x, acc[i][8]);
            acc[i][9]  = fmaf(a, r2.y, acc[i][9]);
            acc[i][10] = fmaf(a, r2.z, acc[i][10]);
            acc[i][11] = fmaf(a, r2.w, acc[i][11]);
            acc[i][12] = fmaf(a, r3.x, acc[i][12]);
            acc[i][13] = fmaf(a, r3.y, acc[i][13]);
            acc[i][14] = fmaf(a, r3.z, acc[i][14]);
            acc[i][15] = fmaf(a, r3.w, acc[i][15]);
        }
    }

    // Layer 3: relu(h2) . W3 + b3, then weighted atomic accumulate into out[b].
    #pragma unroll
    for (int i = 0; i < kNB; ++i) {
        float o = lB3;
        #pragma unroll
        for (int k = 0; k < kH2; ++k) o = fmaf(fmaxf(acc[i][k], 0.f), lW3[k], o);
        atomicAdd(&out[b0 + t + i * kThreads], wgt * o);
    }
}

extern "C" void kernel_launch(void* const* d_in, const int* in_sizes, int n_in,
                              void* d_out, int out_size, void* d_ws, size_t ws_size,
                              hipStream_t stream) {
    const float* x     = (const float*)d_in[0];
    const float* cW1   = (const float*)d_in[1];
    const float* cB1   = (const float*)d_in[2];
    const float* cW2   = (const float*)d_in[3];
    const float* cB2   = (const float*)d_in[4];
    const float* cW3   = (const float*)d_in[5];
    const float* cB3   = (const float*)d_in[6];
    const float* cbias = (const float*)d_in[7];
    const float* sW1   = (const float*)d_in[8];
    const float* sB1   = (const float*)d_in[9];
    const float* sW2   = (const float*)d_in[10];
    const float* sB2   = (const float*)d_in[11];
    const float* sW3   = (const float*)d_in[12];
    const float* sB3   = (const float*)d_in[13];
    const float* sbias = (const float*)d_in[14];
    float* out = (float*)d_out;

    float* xT = (float*)d_ws;
    const int trans = (ws_size >= (size_t)(kB * kF) * sizeof(float)) ? 1 : 0;

    prep_kernel<<<(kB * kF + 255) / 256, 256, 0, stream>>>(x, cbias, sbias, xT, trans, out);
    const float* xin = trans ? (const float*)xT : x;
    nam_kernel<<<(kC + kS) * kF * kChunksPerPair, kThreads, 0, stream>>>(
        xin, trans, cW1, cB1, cW2, cB2, cW3, cB3,
        sW1, sB1, sW2, sB2, sW3, sB3, out);
}